// Round 1
// baseline (1028.563 us; speedup 1.0000x reference)
//
#include <hip/hip_runtime.h>
#include <hip/hip_bf16.h>

#define NFEAT 500
#define DIM   64
#define NCLS  40
#define EPS_FA 0.3f

typedef __attribute__((ext_vector_type(8))) __bf16 bf16x8;
typedef __attribute__((ext_vector_type(4))) float  f32x4;

// ---------------- CSR build ----------------

__global__ __launch_bounds__(256) void hist_kernel(const int* __restrict__ dst,
                                                   int* __restrict__ deg, int E) {
  int e = blockIdx.x * 256 + threadIdx.x;
  if (e < E) atomicAdd(&deg[dst[e]], 1);
}

__global__ __launch_bounds__(1024) void scan_block_kernel(const int* __restrict__ deg,
                                                          int* __restrict__ offs,
                                                          int* __restrict__ bsums, int n) {
  __shared__ int s[1024];
  int t = threadIdx.x;
  int i = blockIdx.x * 1024 + t;
  int v = (i < n) ? deg[i] : 0;
  s[t] = v;
  __syncthreads();
  for (int off = 1; off < 1024; off <<= 1) {
    int add = (t >= off) ? s[t - off] : 0;
    __syncthreads();
    s[t] += add;
    __syncthreads();
  }
  if (i < n) offs[i] = s[t] - v;          // exclusive, block-local
  if (t == 1023) bsums[blockIdx.x] = s[1023];
}

__global__ void scan_sums_kernel(int* __restrict__ bsums, int nb,
                                 int* __restrict__ offs, int n) {
  if (blockIdx.x == 0 && threadIdx.x == 0) {
    int run = 0;
    for (int i = 0; i < nb; ++i) { int v = bsums[i]; bsums[i] = run; run += v; }
    offs[n] = run;                         // == E
  }
}

__global__ __launch_bounds__(1024) void scan_add_kernel(int* __restrict__ offs,
                                                        const int* __restrict__ bsums, int n) {
  int i = blockIdx.x * 1024 + threadIdx.x;
  if (i < n) offs[i] += bsums[blockIdx.x];
}

__global__ __launch_bounds__(256) void scatter_kernel(const int* __restrict__ dst,
                                                      const int* __restrict__ offs,
                                                      int* __restrict__ cursor,
                                                      int* __restrict__ perm, int E) {
  int e = blockIdx.x * 256 + threadIdx.x;
  if (e < E) {
    int d = dst[e];
    int pos = offs[d] + atomicAdd(&cursor[d], 1);
    perm[pos] = e;
  }
}

// ---------------- GEMM1: h = relu(x @ w^T + b), bf16 MFMA ----------------
// tile: 64 nodes x 64 dims, BK=64 (K padded 500->512 with zeros)

__global__ __launch_bounds__(256) void gemm1_kernel(const float* __restrict__ x,
                                                    const float* __restrict__ w,
                                                    const float* __restrict__ bias,
                                                    float* __restrict__ h, int n) {
  __shared__ __bf16 As[64][72];   // [m][k], +8 pad
  __shared__ __bf16 Bs[64][72];   // [d][k]
  const int tid  = threadIdx.x;
  const int lane = tid & 63;
  const int wv   = tid >> 6;          // 4 waves: rows wv*16..wv*16+15
  const int m0   = blockIdx.x * 64;

  f32x4 acc[4];
#pragma unroll
  for (int c = 0; c < 4; ++c) acc[c] = (f32x4){0.f, 0.f, 0.f, 0.f};

  const int rowA = wv * 16 + (lane & 15);
  const int koff = (lane >> 4) * 8;

  for (int kb = 0; kb < 512; kb += 64) {
    // stage A (x tile, f32->bf16) and B (w tile)
#pragma unroll
    for (int r = 0; r < 4; ++r) {
      int idx = r * 256 + tid;
      int m   = idx >> 4;             // 0..63
      int k4  = (idx & 15) << 2;      // 0,4,...,60
      int gk  = kb + k4;
      float4 va = {0.f, 0.f, 0.f, 0.f};
      int gm = m0 + m;
      if (gm < n && gk < NFEAT)
        va = *reinterpret_cast<const float4*>(&x[(size_t)gm * NFEAT + gk]);
      As[m][k4 + 0] = (__bf16)va.x;
      As[m][k4 + 1] = (__bf16)va.y;
      As[m][k4 + 2] = (__bf16)va.z;
      As[m][k4 + 3] = (__bf16)va.w;
      float4 vb = {0.f, 0.f, 0.f, 0.f};
      if (gk < NFEAT)
        vb = *reinterpret_cast<const float4*>(&w[(size_t)m * NFEAT + gk]);
      Bs[m][k4 + 0] = (__bf16)vb.x;
      Bs[m][k4 + 1] = (__bf16)vb.y;
      Bs[m][k4 + 2] = (__bf16)vb.z;
      Bs[m][k4 + 3] = (__bf16)vb.w;
    }
    __syncthreads();
#pragma unroll
    for (int ks = 0; ks < 2; ++ks) {
      int k0 = ks * 32 + koff;
      bf16x8 a = *reinterpret_cast<const bf16x8*>(&As[rowA][k0]);
#pragma unroll
      for (int c = 0; c < 4; ++c) {
        bf16x8 b = *reinterpret_cast<const bf16x8*>(&Bs[c * 16 + (lane & 15)][k0]);
        acc[c] = __builtin_amdgcn_mfma_f32_16x16x32_bf16(a, b, acc[c], 0, 0, 0);
      }
    }
    __syncthreads();
  }

  // epilogue: C/D layout col=lane&15, row=(lane>>4)*4+r  [m89-verified]
#pragma unroll
  for (int c = 0; c < 4; ++c) {
    int col = c * 16 + (lane & 15);
    float bv = bias[col];
#pragma unroll
    for (int r = 0; r < 4; ++r) {
      int gm = m0 + wv * 16 + (lane >> 4) * 4 + r;
      if (gm < n) {
        float v = acc[c][r] + bv;
        h[(size_t)gm * DIM + col] = v > 0.f ? v : 0.f;
      }
    }
  }
}

// ---------------- per-node attention dots ----------------

__global__ __launch_bounds__(256) void dots_kernel(const float* __restrict__ h,
                                                   const float* __restrict__ al,
                                                   const float* __restrict__ ar,
                                                   float* __restrict__ hl,
                                                   float* __restrict__ hr, int n) {
  int gw   = (blockIdx.x * 256 + threadIdx.x) >> 6;  // wave per node
  int lane = threadIdx.x & 63;
  if (gw >= n) return;
  float v = h[(size_t)gw * DIM + lane];
  float a = v * al[lane];
  float b = v * ar[lane];
#pragma unroll
  for (int off = 32; off > 0; off >>= 1) {
    a += __shfl_xor(a, off, 64);
    b += __shfl_xor(b, off, 64);
  }
  if (lane == 0) { hl[gw] = a; hr[gw] = b; }
}

// ---------------- FAConv aggregation (CSR, wave per node) ----------------

__global__ __launch_bounds__(256) void agg_kernel(const float* __restrict__ h,
                                                  const float* __restrict__ raw,
                                                  const int* __restrict__ src,
                                                  const float* __restrict__ ewt,
                                                  const float* __restrict__ hl,
                                                  const float* __restrict__ hr,
                                                  const int* __restrict__ offs,
                                                  const int* __restrict__ perm,
                                                  float* __restrict__ out, int n) {
  int node = (blockIdx.x * 256 + threadIdx.x) >> 6;
  int lane = threadIdx.x & 63;
  if (node >= n) return;
  int e0 = offs[node], e1 = offs[node + 1];
  float hrd = hr[node];
  float acc = 0.f;
  for (int i = e0; i < e1; ++i) {
    int e = perm[i];
    int s = src[e];
    float wv = ewt[e];
    float ew = (__builtin_fabsf(wv) > 0.f) ? (1.f / (1.f + __expf(-wv))) : 0.f;
    float coef = tanhf(hl[s] + hrd) * ew;
    acc += coef * h[(size_t)s * DIM + lane];
  }
  out[(size_t)node * DIM + lane] = EPS_FA * raw[(size_t)node * DIM + lane] + acc;
}

// ---------------- layer-2 aggregation fused with classifier + log_softmax ----------------

__global__ __launch_bounds__(256) void agg_cls_kernel(const float* __restrict__ h,
                                                      const float* __restrict__ raw,
                                                      const int* __restrict__ src,
                                                      const float* __restrict__ ewt,
                                                      const float* __restrict__ hl,
                                                      const float* __restrict__ hr,
                                                      const int* __restrict__ offs,
                                                      const int* __restrict__ perm,
                                                      const float* __restrict__ t2w,
                                                      const float* __restrict__ t2b,
                                                      float* __restrict__ out, int n) {
  __shared__ float rowbuf[4][64];
  int node0 = (blockIdx.x * 256 + threadIdx.x) >> 6;
  int node  = node0 < n ? node0 : n - 1;   // clamp: keep all threads alive for barrier
  int lane  = threadIdx.x & 63;
  int wv    = threadIdx.x >> 6;

  int e0 = offs[node], e1 = offs[node + 1];
  float hrd = hr[node];
  float acc = EPS_FA * raw[(size_t)node * DIM + lane];
  for (int i = e0; i < e1; ++i) {
    int e = perm[i];
    int s = src[e];
    float wvv = ewt[e];
    float ew = (__builtin_fabsf(wvv) > 0.f) ? (1.f / (1.f + __expf(-wvv))) : 0.f;
    float coef = tanhf(hl[s] + hrd) * ew;
    acc += coef * h[(size_t)s * DIM + lane];
  }
  rowbuf[wv][lane] = acc;
  __syncthreads();

  float logit = -1e30f;
  if (lane < NCLS) {
    float d = t2b[lane];
#pragma unroll
    for (int k = 0; k < DIM; ++k) d += rowbuf[wv][k] * t2w[lane * DIM + k];
    logit = d;
  }
  float m = logit;
#pragma unroll
  for (int off = 32; off > 0; off >>= 1) m = fmaxf(m, __shfl_xor(m, off, 64));
  float ex = (lane < NCLS) ? __expf(logit - m) : 0.f;
  float ssum = ex;
#pragma unroll
  for (int off = 32; off > 0; off >>= 1) ssum += __shfl_xor(ssum, off, 64);
  if (node0 < n && lane < NCLS)
    out[(size_t)node * NCLS + lane] = logit - m - __logf(ssum);
}

// ---------------- launch ----------------

extern "C" void kernel_launch(void* const* d_in, const int* in_sizes, int n_in,
                              void* d_out, int out_size, void* d_ws, size_t ws_size,
                              hipStream_t stream) {
  const float* x   = (const float*)d_in[0];
  const int*   ei  = (const int*)d_in[1];
  const float* ewt = (const float*)d_in[2];
  const float* t1w = (const float*)d_in[3];
  const float* t1b = (const float*)d_in[4];
  const float* al1 = (const float*)d_in[5];
  const float* ar1 = (const float*)d_in[6];
  const float* al2 = (const float*)d_in[7];
  const float* ar2 = (const float*)d_in[8];
  const float* t2w = (const float*)d_in[9];
  const float* t2b = (const float*)d_in[10];
  float* out = (float*)d_out;

  const int n = in_sizes[0] / NFEAT;   // 100000
  const int E = in_sizes[2];           // 1600000
  const int* srcp = ei;
  const int* dstp = ei + E;

  char* p = (char*)d_ws;
  auto alloc = [&](size_t bytes) {
    char* q = p;
    p += (bytes + 255) & ~(size_t)255;
    return q;
  };
  float* h0     = (float*)alloc((size_t)n * DIM * 4);
  float* h1     = (float*)alloc((size_t)n * DIM * 4);
  float* hl     = (float*)alloc((size_t)n * 4);
  float* hr     = (float*)alloc((size_t)n * 4);
  int*   deg    = (int*)alloc((size_t)n * 4);
  int*   offs   = (int*)alloc((size_t)(n + 1) * 4);
  int*   cursor = (int*)alloc((size_t)n * 4);
  int*   perm   = (int*)alloc((size_t)E * 4);
  int*   bsums  = (int*)alloc(4096);

  const int nb = (n + 1023) / 1024;

  hipMemsetAsync(deg, 0, (size_t)n * 4, stream);
  hipMemsetAsync(cursor, 0, (size_t)n * 4, stream);

  hist_kernel<<<(E + 255) / 256, 256, 0, stream>>>(dstp, deg, E);
  scan_block_kernel<<<nb, 1024, 0, stream>>>(deg, offs, bsums, n);
  scan_sums_kernel<<<1, 64, 0, stream>>>(bsums, nb, offs, n);
  scan_add_kernel<<<nb, 1024, 0, stream>>>(offs, bsums, n);
  scatter_kernel<<<(E + 255) / 256, 256, 0, stream>>>(dstp, offs, cursor, perm, E);

  gemm1_kernel<<<(n + 63) / 64, 256, 0, stream>>>(x, t1w, t1b, h0, n);
  dots_kernel<<<(n + 3) / 4, 256, 0, stream>>>(h0, al1, ar1, hl, hr, n);
  agg_kernel<<<(n + 3) / 4, 256, 0, stream>>>(h0, h0, srcp, ewt, hl, hr, offs, perm, h1, n);
  dots_kernel<<<(n + 3) / 4, 256, 0, stream>>>(h1, al2, ar2, hl, hr, n);
  agg_cls_kernel<<<(n + 3) / 4, 256, 0, stream>>>(h1, h0, srcp, ewt, hl, hr, offs, perm,
                                                  t2w, t2b, out, n);
}

// Round 2
// 578.117 us; speedup vs baseline: 1.7792x; 1.7792x over previous
//
#include <hip/hip_runtime.h>
#include <hip/hip_bf16.h>

#define NFEAT 500
#define DIM   64
#define NCLS  40
#define EPS_FA 0.3f

typedef __attribute__((ext_vector_type(8))) __bf16 bf16x8;
typedef __attribute__((ext_vector_type(4))) float  f32x4;

__device__ __forceinline__ float bf2f(unsigned short u) {
  return __uint_as_float(((unsigned int)u) << 16);
}
__device__ __forceinline__ float fast_tanh(float x) {
  return 1.f - 2.f / (__expf(2.f * x) + 1.f);   // exact at saturation, no NaN
}

// ---------------- CSR build ----------------

__global__ __launch_bounds__(256) void hist_kernel(const int* __restrict__ dst,
                                                   int* __restrict__ deg, int E) {
  int e = blockIdx.x * 256 + threadIdx.x;
  if (e < E) atomicAdd(&deg[dst[e]], 1);
}

__global__ __launch_bounds__(1024) void scan_block_kernel(const int* __restrict__ deg,
                                                          int* __restrict__ offs,
                                                          int* __restrict__ bsums, int n) {
  __shared__ int s[1024];
  int t = threadIdx.x;
  int i = blockIdx.x * 1024 + t;
  int v = (i < n) ? deg[i] : 0;
  s[t] = v;
  __syncthreads();
  for (int off = 1; off < 1024; off <<= 1) {
    int add = (t >= off) ? s[t - off] : 0;
    __syncthreads();
    s[t] += add;
    __syncthreads();
  }
  if (i < n) offs[i] = s[t] - v;
  if (t == 1023) bsums[blockIdx.x] = s[1023];
}

__global__ void scan_sums_kernel(int* __restrict__ bsums, int nb,
                                 int* __restrict__ offs, int n) {
  if (blockIdx.x == 0 && threadIdx.x == 0) {
    int run = 0;
    for (int i = 0; i < nb; ++i) { int v = bsums[i]; bsums[i] = run; run += v; }
    offs[n] = run;
  }
}

__global__ __launch_bounds__(1024) void scan_add_kernel(int* __restrict__ offs,
                                                        const int* __restrict__ bsums, int n) {
  int i = blockIdx.x * 1024 + threadIdx.x;
  if (i < n) offs[i] += bsums[blockIdx.x];
}

__global__ __launch_bounds__(256) void scatter_kernel(const int* __restrict__ dst,
                                                      const int* __restrict__ offs,
                                                      int* __restrict__ cursor,
                                                      int* __restrict__ perm, int E) {
  int e = blockIdx.x * 256 + threadIdx.x;
  if (e < E) {
    int d = dst[e];
    int pos = offs[d] + atomicAdd(&cursor[d], 1);
    perm[pos] = e;
  }
}

// CSR-ordered edge metadata: srcs[i], dsts[i], masked sigmoid weight ew2[i]
__global__ __launch_bounds__(256) void prep_edges_kernel(const int* __restrict__ src,
                                                         const int* __restrict__ dst,
                                                         const float* __restrict__ ewt,
                                                         const int* __restrict__ perm,
                                                         int* __restrict__ srcs,
                                                         int* __restrict__ dsts,
                                                         float* __restrict__ ew2, int E) {
  int i = blockIdx.x * 256 + threadIdx.x;
  if (i >= E) return;
  int e = perm[i];
  srcs[i] = src[e];
  dsts[i] = dst[e];
  float w = ewt[e];
  ew2[i] = (__builtin_fabsf(w) > 0.f) ? (1.f / (1.f + __expf(-w))) : 0.f;
}

// per-edge coefficient: c[i] = tanh(hl[src]+hr[dst]) * ew2[i]
__global__ __launch_bounds__(256) void coef_kernel(const int* __restrict__ srcs,
                                                   const int* __restrict__ dsts,
                                                   const float* __restrict__ ew2,
                                                   const float* __restrict__ hl,
                                                   const float* __restrict__ hr,
                                                   float* __restrict__ c, int E) {
  int i = blockIdx.x * 256 + threadIdx.x;
  if (i >= E) return;
  c[i] = fast_tanh(hl[srcs[i]] + hr[dsts[i]]) * ew2[i];
}

// ---------------- GEMM1: h = relu(x @ w^T + b), split-bf16 MFMA ----------------
// x = xh + xl, w = wh + wl; acc += xh*wh + xh*wl + xl*wh  (error ~2^-17 rel)

__global__ __launch_bounds__(256) void gemm1_kernel(const float* __restrict__ x,
                                                    const float* __restrict__ w,
                                                    const float* __restrict__ bias,
                                                    float* __restrict__ h,
                                                    unsigned short* __restrict__ hb, int n) {
  __shared__ __bf16 Ah[64][72], Al[64][72], Bh[64][72], Bl[64][72];
  const int tid  = threadIdx.x;
  const int lane = tid & 63;
  const int wv   = tid >> 6;
  const int m0   = blockIdx.x * 64;

  f32x4 acc[4];
#pragma unroll
  for (int c = 0; c < 4; ++c) acc[c] = (f32x4){0.f, 0.f, 0.f, 0.f};

  const int rowA = wv * 16 + (lane & 15);
  const int koff = (lane >> 4) * 8;

  for (int kb = 0; kb < 512; kb += 64) {
#pragma unroll
    for (int r = 0; r < 4; ++r) {
      int idx = r * 256 + tid;
      int m   = idx >> 4;
      int k4  = (idx & 15) << 2;
      int gk  = kb + k4;
      float4 va = {0.f, 0.f, 0.f, 0.f};
      int gm = m0 + m;
      if (gm < n && gk < NFEAT)
        va = *reinterpret_cast<const float4*>(&x[(size_t)gm * NFEAT + gk]);
      float4 vb = {0.f, 0.f, 0.f, 0.f};
      if (gk < NFEAT)
        vb = *reinterpret_cast<const float4*>(&w[(size_t)m * NFEAT + gk]);
#pragma unroll
      for (int q = 0; q < 4; ++q) {
        float fa = (&va.x)[q];
        __bf16 ah = (__bf16)fa;
        Ah[m][k4 + q] = ah;
        Al[m][k4 + q] = (__bf16)(fa - (float)ah);
        float fb = (&vb.x)[q];
        __bf16 bh = (__bf16)fb;
        Bh[m][k4 + q] = bh;
        Bl[m][k4 + q] = (__bf16)(fb - (float)bh);
      }
    }
    __syncthreads();
#pragma unroll
    for (int ks = 0; ks < 2; ++ks) {
      int k0 = ks * 32 + koff;
      bf16x8 a_h = *reinterpret_cast<const bf16x8*>(&Ah[rowA][k0]);
      bf16x8 a_l = *reinterpret_cast<const bf16x8*>(&Al[rowA][k0]);
#pragma unroll
      for (int c = 0; c < 4; ++c) {
        int rb = c * 16 + (lane & 15);
        bf16x8 b_h = *reinterpret_cast<const bf16x8*>(&Bh[rb][k0]);
        bf16x8 b_l = *reinterpret_cast<const bf16x8*>(&Bl[rb][k0]);
        acc[c] = __builtin_amdgcn_mfma_f32_16x16x32_bf16(a_h, b_h, acc[c], 0, 0, 0);
        acc[c] = __builtin_amdgcn_mfma_f32_16x16x32_bf16(a_h, b_l, acc[c], 0, 0, 0);
        acc[c] = __builtin_amdgcn_mfma_f32_16x16x32_bf16(a_l, b_h, acc[c], 0, 0, 0);
      }
    }
    __syncthreads();
  }

#pragma unroll
  for (int c = 0; c < 4; ++c) {
    int col = c * 16 + (lane & 15);
    float bv = bias[col];
#pragma unroll
    for (int r = 0; r < 4; ++r) {
      int gm = m0 + wv * 16 + (lane >> 4) * 4 + r;
      if (gm < n) {
        float v = acc[c][r] + bv;
        v = v > 0.f ? v : 0.f;
        h[(size_t)gm * DIM + col] = v;
        __bf16 vb16 = (__bf16)v;
        hb[(size_t)gm * DIM + col] = *reinterpret_cast<unsigned short*>(&vb16);
      }
    }
  }
}

// ---------------- per-node attention dots ----------------

__global__ __launch_bounds__(256) void dots_kernel(const float* __restrict__ h,
                                                   const float* __restrict__ al,
                                                   const float* __restrict__ ar,
                                                   float* __restrict__ hl,
                                                   float* __restrict__ hr, int n) {
  int gw   = (blockIdx.x * 256 + threadIdx.x) >> 6;
  int lane = threadIdx.x & 63;
  if (gw >= n) return;
  float v = h[(size_t)gw * DIM + lane];
  float a = v * al[lane];
  float b = v * ar[lane];
#pragma unroll
  for (int off = 32; off > 0; off >>= 1) {
    a += __shfl_xor(a, off, 64);
    b += __shfl_xor(b, off, 64);
  }
  if (lane == 0) { hl[gw] = a; hr[gw] = b; }
}

// ---------------- FAConv layer-1 agg + fused layer-2 dots ----------------
// out: h1b (bf16), hl2, hr2.  h1 fp32 never hits HBM.

__global__ __launch_bounds__(256) void agg1_kernel(const unsigned short* __restrict__ hb,
                                                   const float* __restrict__ raw,
                                                   const int* __restrict__ srcs,
                                                   const float* __restrict__ c,
                                                   const int* __restrict__ offs,
                                                   const float* __restrict__ al2,
                                                   const float* __restrict__ ar2,
                                                   unsigned short* __restrict__ h1b,
                                                   float* __restrict__ hl2,
                                                   float* __restrict__ hr2, int n) {
  int node = (blockIdx.x * 256 + threadIdx.x) >> 6;
  int lane = threadIdx.x & 63;
  if (node >= n) return;
  int e0 = offs[node], e1 = offs[node + 1];
  float acc0 = 0.f, acc1 = 0.f;
  for (int base = e0; base < e1; base += 64) {
    int idx = base + lane;
    bool vld = idx < e1;
    int   sv = vld ? srcs[idx] : 0;
    float cv = vld ? c[idx] : 0.f;
    int cnt = e1 - base; if (cnt > 64) cnt = 64;
    int j = 0;
    for (; j + 4 <= cnt; j += 4) {
      int s0 = __shfl(sv, j+0), s1 = __shfl(sv, j+1);
      int s2 = __shfl(sv, j+2), s3 = __shfl(sv, j+3);
      float c0 = __shfl(cv, j+0), c1 = __shfl(cv, j+1);
      float c2 = __shfl(cv, j+2), c3 = __shfl(cv, j+3);
      float v0 = bf2f(hb[(size_t)s0 * DIM + lane]);
      float v1 = bf2f(hb[(size_t)s1 * DIM + lane]);
      float v2 = bf2f(hb[(size_t)s2 * DIM + lane]);
      float v3 = bf2f(hb[(size_t)s3 * DIM + lane]);
      acc0 = fmaf(c0, v0, acc0); acc1 = fmaf(c1, v1, acc1);
      acc0 = fmaf(c2, v2, acc0); acc1 = fmaf(c3, v3, acc1);
    }
    for (; j < cnt; ++j) {
      int   sj = __shfl(sv, j);
      float cj = __shfl(cv, j);
      acc0 = fmaf(cj, bf2f(hb[(size_t)sj * DIM + lane]), acc0);
    }
  }
  float v = EPS_FA * raw[(size_t)node * DIM + lane] + acc0 + acc1;
  __bf16 vb16 = (__bf16)v;
  h1b[(size_t)node * DIM + lane] = *reinterpret_cast<unsigned short*>(&vb16);
  // fused layer-2 dots
  float a = v * al2[lane];
  float b = v * ar2[lane];
#pragma unroll
  for (int off = 32; off > 0; off >>= 1) {
    a += __shfl_xor(a, off, 64);
    b += __shfl_xor(b, off, 64);
  }
  if (lane == 0) { hl2[node] = a; hr2[node] = b; }
}

// ---------------- layer-2 agg fused with classifier + log_softmax ----------------

__global__ __launch_bounds__(256) void agg_cls_kernel(const unsigned short* __restrict__ hb,
                                                      const float* __restrict__ raw,
                                                      const int* __restrict__ srcs,
                                                      const float* __restrict__ c,
                                                      const int* __restrict__ offs,
                                                      const float* __restrict__ t2w,
                                                      const float* __restrict__ t2b,
                                                      float* __restrict__ out, int n) {
  __shared__ float rowbuf[4][64];
  __shared__ float t2s[DIM * NCLS];     // [k][cls]
  int tid = threadIdx.x;
  for (int t = tid; t < DIM * NCLS; t += 256) {
    int k = t / NCLS, cls = t - k * NCLS;
    t2s[t] = t2w[cls * DIM + k];
  }
  int node0 = (blockIdx.x * 256 + tid) >> 6;
  int node  = node0 < n ? node0 : n - 1;
  int lane  = tid & 63;
  int wv    = tid >> 6;

  int e0 = offs[node], e1 = offs[node + 1];
  float acc0 = 0.f, acc1 = 0.f;
  for (int base = e0; base < e1; base += 64) {
    int idx = base + lane;
    bool vld = idx < e1;
    int   sv = vld ? srcs[idx] : 0;
    float cv = vld ? c[idx] : 0.f;
    int cnt = e1 - base; if (cnt > 64) cnt = 64;
    int j = 0;
    for (; j + 4 <= cnt; j += 4) {
      int s0 = __shfl(sv, j+0), s1 = __shfl(sv, j+1);
      int s2 = __shfl(sv, j+2), s3 = __shfl(sv, j+3);
      float c0 = __shfl(cv, j+0), c1 = __shfl(cv, j+1);
      float c2 = __shfl(cv, j+2), c3 = __shfl(cv, j+3);
      float v0 = bf2f(hb[(size_t)s0 * DIM + lane]);
      float v1 = bf2f(hb[(size_t)s1 * DIM + lane]);
      float v2 = bf2f(hb[(size_t)s2 * DIM + lane]);
      float v3 = bf2f(hb[(size_t)s3 * DIM + lane]);
      acc0 = fmaf(c0, v0, acc0); acc1 = fmaf(c1, v1, acc1);
      acc0 = fmaf(c2, v2, acc0); acc1 = fmaf(c3, v3, acc1);
    }
    for (; j < cnt; ++j) {
      int   sj = __shfl(sv, j);
      float cj = __shfl(cv, j);
      acc0 = fmaf(cj, bf2f(hb[(size_t)sj * DIM + lane]), acc0);
    }
  }
  rowbuf[wv][lane] = EPS_FA * raw[(size_t)node * DIM + lane] + acc0 + acc1;
  __syncthreads();

  float logit = -1e30f;
  if (lane < NCLS) {
    float d = t2b[lane];
#pragma unroll
    for (int k = 0; k < DIM; ++k) d = fmaf(rowbuf[wv][k], t2s[k * NCLS + lane], d);
    logit = d;
  }
  float m = logit;
#pragma unroll
  for (int off = 32; off > 0; off >>= 1) m = fmaxf(m, __shfl_xor(m, off, 64));
  float ex = (lane < NCLS) ? __expf(logit - m) : 0.f;
  float ssum = ex;
#pragma unroll
  for (int off = 32; off > 0; off >>= 1) ssum += __shfl_xor(ssum, off, 64);
  if (node0 < n && lane < NCLS)
    out[(size_t)node * NCLS + lane] = logit - m - __logf(ssum);
}

// ---------------- launch ----------------

extern "C" void kernel_launch(void* const* d_in, const int* in_sizes, int n_in,
                              void* d_out, int out_size, void* d_ws, size_t ws_size,
                              hipStream_t stream) {
  const float* x   = (const float*)d_in[0];
  const int*   ei  = (const int*)d_in[1];
  const float* ewt = (const float*)d_in[2];
  const float* t1w = (const float*)d_in[3];
  const float* t1b = (const float*)d_in[4];
  const float* al1 = (const float*)d_in[5];
  const float* ar1 = (const float*)d_in[6];
  const float* al2 = (const float*)d_in[7];
  const float* ar2 = (const float*)d_in[8];
  const float* t2w = (const float*)d_in[9];
  const float* t2b = (const float*)d_in[10];
  float* out = (float*)d_out;

  const int n = in_sizes[0] / NFEAT;   // 100000
  const int E = in_sizes[2];           // 1600000
  const int* srcp = ei;
  const int* dstp = ei + E;

  char* p = (char*)d_ws;
  auto alloc = [&](size_t bytes) {
    char* q = p;
    p += (bytes + 255) & ~(size_t)255;
    return q;
  };
  float*          h0   = (float*)alloc((size_t)n * DIM * 4);
  unsigned short* h0b  = (unsigned short*)alloc((size_t)n * DIM * 2);
  unsigned short* h1b  = (unsigned short*)alloc((size_t)n * DIM * 2);
  float* hl    = (float*)alloc((size_t)n * 4);
  float* hr    = (float*)alloc((size_t)n * 4);
  int*   deg   = (int*)alloc((size_t)n * 4);
  int*   offs  = (int*)alloc((size_t)(n + 1) * 4);
  int*   cursor= (int*)alloc((size_t)n * 4);
  int*   perm  = (int*)alloc((size_t)E * 4);
  int*   srcs  = (int*)alloc((size_t)E * 4);
  int*   dsts  = (int*)alloc((size_t)E * 4);
  float* ew2   = (float*)alloc((size_t)E * 4);
  int*   bsums = (int*)alloc(4096);
  float* coefs = (float*)perm;          // alias: perm dead after prep_edges

  const int nb = (n + 1023) / 1024;
  const int eb = (E + 255) / 256;

  hipMemsetAsync(deg, 0, (size_t)n * 4, stream);
  hipMemsetAsync(cursor, 0, (size_t)n * 4, stream);

  hist_kernel<<<eb, 256, 0, stream>>>(dstp, deg, E);
  scan_block_kernel<<<nb, 1024, 0, stream>>>(deg, offs, bsums, n);
  scan_sums_kernel<<<1, 64, 0, stream>>>(bsums, nb, offs, n);
  scan_add_kernel<<<nb, 1024, 0, stream>>>(offs, bsums, n);
  scatter_kernel<<<eb, 256, 0, stream>>>(dstp, offs, cursor, perm, E);
  prep_edges_kernel<<<eb, 256, 0, stream>>>(srcp, dstp, ewt, perm, srcs, dsts, ew2, E);

  gemm1_kernel<<<(n + 63) / 64, 256, 0, stream>>>(x, t1w, t1b, h0, h0b, n);
  dots_kernel<<<(n + 3) / 4, 256, 0, stream>>>(h0, al1, ar1, hl, hr, n);
  coef_kernel<<<eb, 256, 0, stream>>>(srcs, dsts, ew2, hl, hr, coefs, E);
  agg1_kernel<<<(n + 3) / 4, 256, 0, stream>>>(h0b, h0, srcs, coefs, offs, al2, ar2,
                                               h1b, hl, hr, n);
  coef_kernel<<<eb, 256, 0, stream>>>(srcs, dsts, ew2, hl, hr, coefs, E);
  agg_cls_kernel<<<(n + 3) / 4, 256, 0, stream>>>(h1b, h0, srcs, coefs, offs,
                                                  t2w, t2b, out, n);
}

// Round 3
// 553.846 us; speedup vs baseline: 1.8571x; 1.0438x over previous
//
#include <hip/hip_runtime.h>
#include <hip/hip_bf16.h>

#define NFEAT 500
#define DIM   64
#define NCLS  40
#define EPS_FA 0.3f
#define NPB   16      // nodes per agg block
#define LDSE  1024    // staged edges per block (mean 256, 32 sigma headroom)

typedef __attribute__((ext_vector_type(8))) __bf16 bf16x8;
typedef __attribute__((ext_vector_type(4))) float  f32x4;

__device__ __forceinline__ float bf2f(unsigned short u) {
  return __uint_as_float(((unsigned int)u) << 16);
}
__device__ __forceinline__ float fast_tanh(float x) {
  return 1.f - 2.f / (__expf(2.f * x) + 1.f);
}

// ---------------- CSR build ----------------

__global__ __launch_bounds__(256) void hist_kernel(const int* __restrict__ dst,
                                                   int* __restrict__ deg, int E) {
  int e = blockIdx.x * 256 + threadIdx.x;
  if (e < E) atomicAdd(&deg[dst[e]], 1);
}

__global__ __launch_bounds__(1024) void scan_block_kernel(const int* __restrict__ deg,
                                                          int* __restrict__ offs,
                                                          int* __restrict__ bsums, int n) {
  __shared__ int s[1024];
  int t = threadIdx.x;
  int i = blockIdx.x * 1024 + t;
  int v = (i < n) ? deg[i] : 0;
  s[t] = v;
  __syncthreads();
  for (int off = 1; off < 1024; off <<= 1) {
    int add = (t >= off) ? s[t - off] : 0;
    __syncthreads();
    s[t] += add;
    __syncthreads();
  }
  if (i < n) offs[i] = s[t] - v;
  if (t == 1023) bsums[blockIdx.x] = s[1023];
}

__global__ void scan_sums_kernel(int* __restrict__ bsums, int nb,
                                 int* __restrict__ offs, int n) {
  if (blockIdx.x == 0 && threadIdx.x == 0) {
    int run = 0;
    for (int i = 0; i < nb; ++i) { int v = bsums[i]; bsums[i] = run; run += v; }
    offs[n] = run;
  }
}

__global__ __launch_bounds__(1024) void scan_add_kernel(int* __restrict__ offs,
                                                        const int* __restrict__ bsums, int n) {
  int i = blockIdx.x * 1024 + threadIdx.x;
  if (i < n) offs[i] += bsums[blockIdx.x];
}

__global__ __launch_bounds__(256) void scatter_kernel(const int* __restrict__ dst,
                                                      const int* __restrict__ offs,
                                                      int* __restrict__ cursor,
                                                      int* __restrict__ perm, int E) {
  int e = blockIdx.x * 256 + threadIdx.x;
  if (e < E) {
    int d = dst[e];
    int pos = offs[d] + atomicAdd(&cursor[d], 1);
    perm[pos] = e;
  }
}

__global__ __launch_bounds__(256) void prep_edges_kernel(const int* __restrict__ src,
                                                         const int* __restrict__ dst,
                                                         const float* __restrict__ ewt,
                                                         const int* __restrict__ perm,
                                                         int* __restrict__ srcs,
                                                         int* __restrict__ dsts,
                                                         float* __restrict__ ew2, int E) {
  int i = blockIdx.x * 256 + threadIdx.x;
  if (i >= E) return;
  int e = perm[i];
  srcs[i] = src[e];
  dsts[i] = dst[e];
  float w = ewt[e];
  ew2[i] = (__builtin_fabsf(w) > 0.f) ? (1.f / (1.f + __expf(-w))) : 0.f;
}

// per-edge packed metadata: {src byte-offset into bf16 table, coef}
__global__ __launch_bounds__(256) void coef_kernel(const int* __restrict__ srcs,
                                                   const int* __restrict__ dsts,
                                                   const float* __restrict__ ew2,
                                                   const float* __restrict__ hl,
                                                   const float* __restrict__ hr,
                                                   int2* __restrict__ edata, int E) {
  int i = blockIdx.x * 256 + threadIdx.x;
  if (i >= E) return;
  float c = fast_tanh(hl[srcs[i]] + hr[dsts[i]]) * ew2[i];
  edata[i] = make_int2(srcs[i] * (DIM * 2), __float_as_int(c));
}

// ---------------- GEMM1: h = relu(x @ w^T + b), split-bf16 MFMA ----------------

__global__ __launch_bounds__(256) void gemm1_kernel(const float* __restrict__ x,
                                                    const float* __restrict__ w,
                                                    const float* __restrict__ bias,
                                                    unsigned short* __restrict__ hb, int n) {
  __shared__ __bf16 Ah[64][72], Al[64][72], Bh[64][72], Bl[64][72];
  const int tid  = threadIdx.x;
  const int lane = tid & 63;
  const int wv   = tid >> 6;
  const int m0   = blockIdx.x * 64;

  f32x4 acc[4];
#pragma unroll
  for (int c = 0; c < 4; ++c) acc[c] = (f32x4){0.f, 0.f, 0.f, 0.f};

  const int rowA = wv * 16 + (lane & 15);
  const int koff = (lane >> 4) * 8;

  for (int kb = 0; kb < 512; kb += 64) {
#pragma unroll
    for (int r = 0; r < 4; ++r) {
      int idx = r * 256 + tid;
      int m   = idx >> 4;
      int k4  = (idx & 15) << 2;
      int gk  = kb + k4;
      float4 va = {0.f, 0.f, 0.f, 0.f};
      int gm = m0 + m;
      if (gm < n && gk < NFEAT)
        va = *reinterpret_cast<const float4*>(&x[(size_t)gm * NFEAT + gk]);
      float4 vb = {0.f, 0.f, 0.f, 0.f};
      if (gk < NFEAT)
        vb = *reinterpret_cast<const float4*>(&w[(size_t)m * NFEAT + gk]);
#pragma unroll
      for (int q = 0; q < 4; ++q) {
        float fa = (&va.x)[q];
        __bf16 ah = (__bf16)fa;
        Ah[m][k4 + q] = ah;
        Al[m][k4 + q] = (__bf16)(fa - (float)ah);
        float fb = (&vb.x)[q];
        __bf16 bh = (__bf16)fb;
        Bh[m][k4 + q] = bh;
        Bl[m][k4 + q] = (__bf16)(fb - (float)bh);
      }
    }
    __syncthreads();
#pragma unroll
    for (int ks = 0; ks < 2; ++ks) {
      int k0 = ks * 32 + koff;
      bf16x8 a_h = *reinterpret_cast<const bf16x8*>(&Ah[rowA][k0]);
      bf16x8 a_l = *reinterpret_cast<const bf16x8*>(&Al[rowA][k0]);
#pragma unroll
      for (int c = 0; c < 4; ++c) {
        int rb = c * 16 + (lane & 15);
        bf16x8 b_h = *reinterpret_cast<const bf16x8*>(&Bh[rb][k0]);
        bf16x8 b_l = *reinterpret_cast<const bf16x8*>(&Bl[rb][k0]);
        acc[c] = __builtin_amdgcn_mfma_f32_16x16x32_bf16(a_h, b_h, acc[c], 0, 0, 0);
        acc[c] = __builtin_amdgcn_mfma_f32_16x16x32_bf16(a_h, b_l, acc[c], 0, 0, 0);
        acc[c] = __builtin_amdgcn_mfma_f32_16x16x32_bf16(a_l, b_h, acc[c], 0, 0, 0);
      }
    }
    __syncthreads();
  }

#pragma unroll
  for (int c = 0; c < 4; ++c) {
    int col = c * 16 + (lane & 15);
    float bv = bias[col];
#pragma unroll
    for (int r = 0; r < 4; ++r) {
      int gm = m0 + wv * 16 + (lane >> 4) * 4 + r;
      if (gm < n) {
        float v = acc[c][r] + bv;
        v = v > 0.f ? v : 0.f;
        __bf16 vb16 = (__bf16)v;
        hb[(size_t)gm * DIM + col] = *reinterpret_cast<unsigned short*>(&vb16);
      }
    }
  }
}

// ---------------- per-node attention dots (layer 1, from bf16 h) ----------------

__global__ __launch_bounds__(256) void dots_kernel(const unsigned short* __restrict__ hb,
                                                   const float* __restrict__ al,
                                                   const float* __restrict__ ar,
                                                   float* __restrict__ hl,
                                                   float* __restrict__ hr, int n) {
  int gw   = (blockIdx.x * 256 + threadIdx.x) >> 6;
  int lane = threadIdx.x & 63;
  if (gw >= n) return;
  float v = bf2f(hb[(size_t)gw * DIM + lane]);
  float a = v * al[lane];
  float b = v * ar[lane];
#pragma unroll
  for (int off = 32; off > 0; off >>= 1) {
    a += __shfl_xor(a, off, 64);
    b += __shfl_xor(b, off, 64);
  }
  if (lane == 0) { hl[gw] = a; hr[gw] = b; }
}

// ---------------- shared agg inner loop ----------------
// Returns sum over CSR range [s,t) (block-relative; edges < LDSE come from LDS).

__device__ __forceinline__ float agg_edges(const int2* __restrict__ eds,     // LDS
                                           const int2* __restrict__ edata,   // global
                                           const unsigned short* __restrict__ hb,
                                           int s, int t, int e0, int lane2) {
  float acc = 0.f;
  int lim = t < LDSE ? t : LDSE;
  int j = s < lim ? s : lim;
  for (; j + 8 <= lim; j += 8) {
    int2 Ev[8];
#pragma unroll
    for (int q = 0; q < 8; ++q) Ev[q] = eds[j + q];
    float v[8];
#pragma unroll
    for (int q = 0; q < 8; ++q)
      v[q] = bf2f(*(const unsigned short*)((const char*)hb + Ev[q].x + lane2));
#pragma unroll
    for (int q = 0; q < 8; ++q)
      acc = fmaf(__int_as_float(Ev[q].y), v[q], acc);
  }
  for (; j < lim; ++j) {
    int2 e = eds[j];
    acc = fmaf(__int_as_float(e.y),
               bf2f(*(const unsigned short*)((const char*)hb + e.x + lane2)), acc);
  }
  for (j = (s > lim ? s : lim); j < t; ++j) {   // LDS overflow fallback (never hit)
    int2 e = edata[e0 + j];
    acc = fmaf(__int_as_float(e.y),
               bf2f(*(const unsigned short*)((const char*)hb + e.x + lane2)), acc);
  }
  return acc;
}

// ---------------- FAConv layer-1 agg + fused layer-2 dots ----------------

__global__ __launch_bounds__(256) void agg1_kernel(const unsigned short* __restrict__ hb,
                                                   const int2* __restrict__ edata,
                                                   const int* __restrict__ offs,
                                                   const float* __restrict__ al2,
                                                   const float* __restrict__ ar2,
                                                   unsigned short* __restrict__ h1b,
                                                   float* __restrict__ hl2,
                                                   float* __restrict__ hr2, int n) {
  __shared__ int2 eds[LDSE];
  const int tid  = threadIdx.x;
  const int lane = tid & 63;
  const int wv   = tid >> 6;
  const int n0   = blockIdx.x * NPB;
  const int e0   = offs[n0];
  const int eEnd = offs[n0 + NPB < n ? n0 + NPB : n];
  const int nE   = eEnd - e0;
  for (int i = tid; i < nE && i < LDSE; i += 256) eds[i] = edata[e0 + i];
  __syncthreads();

  const int lane2 = lane << 1;
#pragma unroll
  for (int r = 0; r < 4; ++r) {
    int node = n0 + wv * 4 + r;
    if (node >= n) break;
    int s = offs[node] - e0, t = offs[node + 1] - e0;
    float acc = agg_edges(eds, edata, hb, s, t, e0, lane2);
    float v = EPS_FA * bf2f(hb[(size_t)node * DIM + lane]) + acc;
    __bf16 vb16 = (__bf16)v;
    h1b[(size_t)node * DIM + lane] = *reinterpret_cast<unsigned short*>(&vb16);
    float a = v * al2[lane];
    float b = v * ar2[lane];
#pragma unroll
    for (int off = 32; off > 0; off >>= 1) {
      a += __shfl_xor(a, off, 64);
      b += __shfl_xor(b, off, 64);
    }
    if (lane == 0) { hl2[node] = a; hr2[node] = b; }
  }
}

// ---------------- layer-2 agg fused with classifier + log_softmax ----------------

__global__ __launch_bounds__(256) void agg_cls_kernel(const unsigned short* __restrict__ hb,
                                                      const unsigned short* __restrict__ rawb,
                                                      const int2* __restrict__ edata,
                                                      const int* __restrict__ offs,
                                                      const float* __restrict__ t2w,
                                                      const float* __restrict__ t2b,
                                                      float* __restrict__ out, int n) {
  __shared__ int2 eds[LDSE];
  __shared__ float t2s[DIM * NCLS];     // [k][cls]
  __shared__ float rowbuf[4][64];       // per-wave slot
  const int tid  = threadIdx.x;
  const int lane = tid & 63;
  const int wv   = tid >> 6;
  const int n0   = blockIdx.x * NPB;
  const int e0   = offs[n0];
  const int eEnd = offs[n0 + NPB < n ? n0 + NPB : n];
  const int nE   = eEnd - e0;
  for (int i = tid; i < nE && i < LDSE; i += 256) eds[i] = edata[e0 + i];
  for (int i = tid; i < DIM * NCLS; i += 256) {
    int k = i / NCLS, cls = i - k * NCLS;
    t2s[i] = t2w[cls * DIM + k];
  }
  __syncthreads();

  const int lane2 = lane << 1;
#pragma unroll
  for (int r = 0; r < 4; ++r) {
    int node = n0 + wv * 4 + r;
    if (node >= n) break;
    int s = offs[node] - e0, t = offs[node + 1] - e0;
    float acc = agg_edges(eds, edata, hb, s, t, e0, lane2);
    rowbuf[wv][lane] = EPS_FA * bf2f(rawb[(size_t)node * DIM + lane]) + acc;
    // wave-local LDS RAW: in-order DS pipe + lgkmcnt, no barrier needed
    float logit = -1e30f;
    if (lane < NCLS) {
      float d = t2b[lane];
#pragma unroll
      for (int k = 0; k < DIM; ++k) d = fmaf(rowbuf[wv][k], t2s[k * NCLS + lane], d);
      logit = d;
    }
    float m = logit;
#pragma unroll
    for (int off = 32; off > 0; off >>= 1) m = fmaxf(m, __shfl_xor(m, off, 64));
    float ex = (lane < NCLS) ? __expf(logit - m) : 0.f;
    float ssum = ex;
#pragma unroll
    for (int off = 32; off > 0; off >>= 1) ssum += __shfl_xor(ssum, off, 64);
    if (lane < NCLS)
      out[(size_t)node * NCLS + lane] = logit - m - __logf(ssum);
  }
}

// ---------------- launch ----------------

extern "C" void kernel_launch(void* const* d_in, const int* in_sizes, int n_in,
                              void* d_out, int out_size, void* d_ws, size_t ws_size,
                              hipStream_t stream) {
  const float* x   = (const float*)d_in[0];
  const int*   ei  = (const int*)d_in[1];
  const float* ewt = (const float*)d_in[2];
  const float* t1w = (const float*)d_in[3];
  const float* t1b = (const float*)d_in[4];
  const float* al1 = (const float*)d_in[5];
  const float* ar1 = (const float*)d_in[6];
  const float* al2 = (const float*)d_in[7];
  const float* ar2 = (const float*)d_in[8];
  const float* t2w = (const float*)d_in[9];
  const float* t2b = (const float*)d_in[10];
  float* out = (float*)d_out;

  const int n = in_sizes[0] / NFEAT;   // 100000
  const int E = in_sizes[2];           // 1600000
  const int* srcp = ei;
  const int* dstp = ei + E;

  char* p = (char*)d_ws;
  auto alloc = [&](size_t bytes) {
    char* q = p;
    p += (bytes + 255) & ~(size_t)255;
    return q;
  };
  unsigned short* h0b  = (unsigned short*)alloc((size_t)n * DIM * 2);
  unsigned short* h1b  = (unsigned short*)alloc((size_t)n * DIM * 2);
  float* hl    = (float*)alloc((size_t)n * 4);
  float* hr    = (float*)alloc((size_t)n * 4);
  int*   offs  = (int*)alloc((size_t)(n + 1) * 4);
  int*   srcs  = (int*)alloc((size_t)E * 4);
  int*   dsts  = (int*)alloc((size_t)E * 4);
  float* ew2   = (float*)alloc((size_t)E * 4);
  int2*  edata = (int2*)alloc((size_t)E * 8);
  // transients live inside the (not-yet-live) edata region
  int* deg    = (int*)edata;                       // n*4 = 400 KB
  int* cursor = (int*)((char*)edata + 0x80000);    // +512 KB
  int* perm   = (int*)((char*)edata + 0x100000);   // +1 MB, E*4 = 6.4 MB
  int* bsums  = (int*)((char*)edata + 0x780000);   // +7.5 MB, 4 KB

  const int nb = (n + 1023) / 1024;
  const int eb = (E + 255) / 256;

  hipMemsetAsync(deg, 0, (size_t)n * 4, stream);
  hipMemsetAsync(cursor, 0, (size_t)n * 4, stream);

  hist_kernel<<<eb, 256, 0, stream>>>(dstp, deg, E);
  scan_block_kernel<<<nb, 1024, 0, stream>>>(deg, offs, bsums, n);
  scan_sums_kernel<<<1, 64, 0, stream>>>(bsums, nb, offs, n);
  scan_add_kernel<<<nb, 1024, 0, stream>>>(offs, bsums, n);
  scatter_kernel<<<eb, 256, 0, stream>>>(dstp, offs, cursor, perm, E);
  prep_edges_kernel<<<eb, 256, 0, stream>>>(srcp, dstp, ewt, perm, srcs, dsts, ew2, E);

  gemm1_kernel<<<(n + 63) / 64, 256, 0, stream>>>(x, t1w, t1b, h0b, n);
  dots_kernel<<<(n + 3) / 4, 256, 0, stream>>>(h0b, al1, ar1, hl, hr, n);
  coef_kernel<<<eb, 256, 0, stream>>>(srcs, dsts, ew2, hl, hr, edata, E);

  const int ab = (n + NPB - 1) / NPB;
  agg1_kernel<<<ab, 256, 0, stream>>>(h0b, edata, offs, al2, ar2, h1b, hl, hr, n);
  coef_kernel<<<eb, 256, 0, stream>>>(srcs, dsts, ew2, hl, hr, edata, E);
  agg_cls_kernel<<<ab, 256, 0, stream>>>(h1b, h0b, edata, offs, t2w, t2b, out, n);
}

// Round 4
// 438.804 us; speedup vs baseline: 2.3440x; 1.2622x over previous
//
#include <hip/hip_runtime.h>
#include <hip/hip_bf16.h>

#define NFEAT 500
#define DIM   64
#define NCLS  40
#define EPS_FA 0.3f
#define NPB   16      // nodes per agg block (4 waves x 4 groups)
#define LDSE  1024    // staged edges per block (mean 256, huge sigma headroom)

typedef __attribute__((ext_vector_type(8))) __bf16 bf16x8;
typedef __attribute__((ext_vector_type(4))) float  f32x4;

__device__ __forceinline__ float bf2f(unsigned short u) {
  return __uint_as_float(((unsigned int)u) << 16);
}
__device__ __forceinline__ float fast_tanh(float x) {
  return 1.f - 2.f / (__expf(2.f * x) + 1.f);
}
__device__ __forceinline__ unsigned int packbf(float a, float b) {
  __bf16 x = (__bf16)a, y = (__bf16)b;
  unsigned short ux = *(unsigned short*)&x, uy = *(unsigned short*)&y;
  return (unsigned int)ux | ((unsigned int)uy << 16);
}

// ---------------- CSR build ----------------

__global__ __launch_bounds__(256) void hist_kernel(const int* __restrict__ dst,
                                                   int* __restrict__ deg, int E) {
  int e = blockIdx.x * 256 + threadIdx.x;
  if (e < E) atomicAdd(&deg[dst[e]], 1);
}

__global__ __launch_bounds__(1024) void scan_block_kernel(const int* __restrict__ deg,
                                                          int* __restrict__ offs,
                                                          int* __restrict__ bsums, int n) {
  __shared__ int s[1024];
  int t = threadIdx.x;
  int i = blockIdx.x * 1024 + t;
  int v = (i < n) ? deg[i] : 0;
  s[t] = v;
  __syncthreads();
  for (int off = 1; off < 1024; off <<= 1) {
    int add = (t >= off) ? s[t - off] : 0;
    __syncthreads();
    s[t] += add;
    __syncthreads();
  }
  if (i < n) offs[i] = s[t] - v;
  if (t == 1023) bsums[blockIdx.x] = s[1023];
}

__global__ void scan_sums_kernel(int* __restrict__ bsums, int nb,
                                 int* __restrict__ offs, int n) {
  if (blockIdx.x == 0 && threadIdx.x == 0) {
    int run = 0;
    for (int i = 0; i < nb; ++i) { int v = bsums[i]; bsums[i] = run; run += v; }
    offs[n] = run;
  }
}

__global__ __launch_bounds__(1024) void scan_add_kernel(int* __restrict__ offs,
                                                        const int* __restrict__ bsums, int n) {
  int i = blockIdx.x * 1024 + threadIdx.x;
  if (i < n) offs[i] += bsums[blockIdx.x];
}

// scatter edge VALUES directly into CSR order (no perm, no prep pass)
__global__ __launch_bounds__(256) void scatter_kernel(const int* __restrict__ src,
                                                      const int* __restrict__ dst,
                                                      const float* __restrict__ ewt,
                                                      const int* __restrict__ offs,
                                                      int* __restrict__ cursor,
                                                      int* __restrict__ srcs,
                                                      int* __restrict__ dsts,
                                                      float* __restrict__ ew2, int E) {
  int e = blockIdx.x * 256 + threadIdx.x;
  if (e >= E) return;
  int d = dst[e];
  int pos = offs[d] + atomicAdd(&cursor[d], 1);
  srcs[pos] = src[e];
  dsts[pos] = d;
  float w = ewt[e];
  ew2[pos] = (__builtin_fabsf(w) > 0.f) ? (1.f / (1.f + __expf(-w))) : 0.f;
}

// per-edge packed metadata: {src byte-offset into bf16 table, coef}
__global__ __launch_bounds__(256) void coef_kernel(const int* __restrict__ srcs,
                                                   const int* __restrict__ dsts,
                                                   const float* __restrict__ ew2,
                                                   const float* __restrict__ hl,
                                                   const float* __restrict__ hr,
                                                   int2* __restrict__ edata, int E) {
  int i = blockIdx.x * 256 + threadIdx.x;
  if (i >= E) return;
  float c = fast_tanh(hl[srcs[i]] + hr[dsts[i]]) * ew2[i];
  edata[i] = make_int2(srcs[i] * (DIM * 2), __float_as_int(c));
}

// ---------------- GEMM1: h = relu(x @ w^T + b), split-bf16 MFMA ----------------

__global__ __launch_bounds__(256) void gemm1_kernel(const float* __restrict__ x,
                                                    const float* __restrict__ w,
                                                    const float* __restrict__ bias,
                                                    unsigned short* __restrict__ hb, int n) {
  __shared__ __bf16 Ah[64][72], Al[64][72], Bh[64][72], Bl[64][72];
  const int tid  = threadIdx.x;
  const int lane = tid & 63;
  const int wv   = tid >> 6;
  const int m0   = blockIdx.x * 64;

  f32x4 acc[4];
#pragma unroll
  for (int c = 0; c < 4; ++c) acc[c] = (f32x4){0.f, 0.f, 0.f, 0.f};

  const int rowA = wv * 16 + (lane & 15);
  const int koff = (lane >> 4) * 8;

  for (int kb = 0; kb < 512; kb += 64) {
#pragma unroll
    for (int r = 0; r < 4; ++r) {
      int idx = r * 256 + tid;
      int m   = idx >> 4;
      int k4  = (idx & 15) << 2;
      int gk  = kb + k4;
      float4 va = {0.f, 0.f, 0.f, 0.f};
      int gm = m0 + m;
      if (gm < n && gk < NFEAT)
        va = *reinterpret_cast<const float4*>(&x[(size_t)gm * NFEAT + gk]);
      float4 vb = {0.f, 0.f, 0.f, 0.f};
      if (gk < NFEAT)
        vb = *reinterpret_cast<const float4*>(&w[(size_t)m * NFEAT + gk]);
#pragma unroll
      for (int q = 0; q < 4; ++q) {
        float fa = (&va.x)[q];
        __bf16 ah = (__bf16)fa;
        Ah[m][k4 + q] = ah;
        Al[m][k4 + q] = (__bf16)(fa - (float)ah);
        float fb = (&vb.x)[q];
        __bf16 bh = (__bf16)fb;
        Bh[m][k4 + q] = bh;
        Bl[m][k4 + q] = (__bf16)(fb - (float)bh);
      }
    }
    __syncthreads();
#pragma unroll
    for (int ks = 0; ks < 2; ++ks) {
      int k0 = ks * 32 + koff;
      bf16x8 a_h = *reinterpret_cast<const bf16x8*>(&Ah[rowA][k0]);
      bf16x8 a_l = *reinterpret_cast<const bf16x8*>(&Al[rowA][k0]);
#pragma unroll
      for (int c = 0; c < 4; ++c) {
        int rb = c * 16 + (lane & 15);
        bf16x8 b_h = *reinterpret_cast<const bf16x8*>(&Bh[rb][k0]);
        bf16x8 b_l = *reinterpret_cast<const bf16x8*>(&Bl[rb][k0]);
        acc[c] = __builtin_amdgcn_mfma_f32_16x16x32_bf16(a_h, b_h, acc[c], 0, 0, 0);
        acc[c] = __builtin_amdgcn_mfma_f32_16x16x32_bf16(a_h, b_l, acc[c], 0, 0, 0);
        acc[c] = __builtin_amdgcn_mfma_f32_16x16x32_bf16(a_l, b_h, acc[c], 0, 0, 0);
      }
    }
    __syncthreads();
  }

#pragma unroll
  for (int c = 0; c < 4; ++c) {
    int col = c * 16 + (lane & 15);
    float bv = bias[col];
#pragma unroll
    for (int r = 0; r < 4; ++r) {
      int gm = m0 + wv * 16 + (lane >> 4) * 4 + r;
      if (gm < n) {
        float v = acc[c][r] + bv;
        v = v > 0.f ? v : 0.f;
        __bf16 vb16 = (__bf16)v;
        hb[(size_t)gm * DIM + col] = *reinterpret_cast<unsigned short*>(&vb16);
      }
    }
  }
}

// ---------------- per-node attention dots (layer 1) ----------------

__global__ __launch_bounds__(256) void dots_kernel(const unsigned short* __restrict__ hb,
                                                   const float* __restrict__ al,
                                                   const float* __restrict__ ar,
                                                   float* __restrict__ hl,
                                                   float* __restrict__ hr, int n) {
  int gw   = (blockIdx.x * 256 + threadIdx.x) >> 6;
  int lane = threadIdx.x & 63;
  if (gw >= n) return;
  float v = bf2f(hb[(size_t)gw * DIM + lane]);
  float a = v * al[lane];
  float b = v * ar[lane];
#pragma unroll
  for (int off = 32; off > 0; off >>= 1) {
    a += __shfl_xor(a, off, 64);
    b += __shfl_xor(b, off, 64);
  }
  if (lane == 0) { hl[gw] = a; hr[gw] = b; }
}

// ---------------- 4-stream edge loop (one 16-lane group per node) ----------------
// Each group gathers its node's edges; lane q owns dims q*4..q*4+3 (8B ushort4).
// One global_load_dwordx2 instruction services 4 edges (4 groups) = 512B payload;
// unroll-8 => 32 loads in flight per wave.

#define EDGE_LOOP(READ_ED)                                                   \
  for (int j = 0; j < mcnt; j += 8) {                                        \
    _Pragma("unroll")                                                        \
    for (int u = 0; u < 8; ++u) {                                            \
      int idx = j + u;                                                       \
      bool valid = idx < cnt;                                                \
      int ci = valid ? s + idx : 0;                                          \
      int2 ed = READ_ED(ci);                                                 \
      int off = valid ? ed.x : 0;                                            \
      float cf = valid ? __int_as_float(ed.y) : 0.f;                         \
      uint2 hv = *reinterpret_cast<const uint2*>((const char*)hb + off + q8);\
      acc.x = fmaf(cf, __uint_as_float(hv.x << 16), acc.x);                  \
      acc.y = fmaf(cf, __uint_as_float(hv.x & 0xffff0000u), acc.y);          \
      acc.z = fmaf(cf, __uint_as_float(hv.y << 16), acc.z);                  \
      acc.w = fmaf(cf, __uint_as_float(hv.y & 0xffff0000u), acc.w);          \
    }                                                                        \
  }
#define RD_LDS(ci) eds[ci]
#define RD_GLB(ci) edata[e0 + (ci)]

// ---------------- FAConv layer-1 agg + fused layer-2 dots ----------------

__global__ __launch_bounds__(256) void agg1_kernel(const unsigned short* __restrict__ hb,
                                                   const int2* __restrict__ edata,
                                                   const int* __restrict__ offs,
                                                   const float* __restrict__ al2,
                                                   const float* __restrict__ ar2,
                                                   unsigned short* __restrict__ h1b,
                                                   float* __restrict__ hl2,
                                                   float* __restrict__ hr2, int n) {
  __shared__ int2 eds[LDSE];
  const int tid  = threadIdx.x;
  const int lane = tid & 63;
  const int wv   = tid >> 6;
  const int g    = lane >> 4;          // group 0..3 -> node
  const int q    = lane & 15;          // dim quad
  const int q8   = q << 3;
  const int n0   = blockIdx.x * NPB;
  const int e0   = offs[n0];
  const int nEnd = n0 + NPB < n ? n0 + NPB : n;
  const int nE   = offs[nEnd] - e0;
  for (int i = tid; i < nE && i < LDSE; i += 256) eds[i] = edata[e0 + i];
  __syncthreads();

  const int node = n0 + wv * 4 + g;
  int s = 0, cnt = 0;
  if (node < n) { s = offs[node] - e0; cnt = offs[node + 1] - e0 - s; }
  int mcnt = cnt;
  mcnt = max(mcnt, __shfl_xor(mcnt, 16, 64));
  mcnt = max(mcnt, __shfl_xor(mcnt, 32, 64));

  float4 acc = {0.f, 0.f, 0.f, 0.f};
  if (nE <= LDSE) { EDGE_LOOP(RD_LDS) } else { EDGE_LOOP(RD_GLB) }

  if (node < n) {
    uint2 rv = *reinterpret_cast<const uint2*>((const char*)hb + (size_t)node * 128 + q8);
    float v0 = fmaf(EPS_FA, __uint_as_float(rv.x << 16),         acc.x);
    float v1 = fmaf(EPS_FA, __uint_as_float(rv.x & 0xffff0000u), acc.y);
    float v2 = fmaf(EPS_FA, __uint_as_float(rv.y << 16),         acc.z);
    float v3 = fmaf(EPS_FA, __uint_as_float(rv.y & 0xffff0000u), acc.w);
    uint2 pk = make_uint2(packbf(v0, v1), packbf(v2, v3));
    *reinterpret_cast<uint2*>((char*)h1b + (size_t)node * 128 + q8) = pk;
    // fused layer-2 dots (16-lane group reduce)
    const float4 alv = *reinterpret_cast<const float4*>(al2 + q * 4);
    const float4 arv = *reinterpret_cast<const float4*>(ar2 + q * 4);
    float a = v0 * alv.x + v1 * alv.y + v2 * alv.z + v3 * alv.w;
    float b = v0 * arv.x + v1 * arv.y + v2 * arv.z + v3 * arv.w;
#pragma unroll
    for (int off = 8; off > 0; off >>= 1) {
      a += __shfl_xor(a, off, 64);
      b += __shfl_xor(b, off, 64);
    }
    if (q == 0) { hl2[node] = a; hr2[node] = b; }
  }
}

// ---------------- layer-2 agg fused with classifier + log_softmax ----------------

__global__ __launch_bounds__(256) void agg_cls_kernel(const unsigned short* __restrict__ hb,
                                                      const unsigned short* __restrict__ rawb,
                                                      const int2* __restrict__ edata,
                                                      const int* __restrict__ offs,
                                                      const float* __restrict__ t2w,
                                                      const float* __restrict__ t2b,
                                                      float* __restrict__ out, int n) {
  __shared__ int2 eds[LDSE];
  __shared__ float t2s[DIM * NCLS];     // [k][cls]
  __shared__ float rowbuf[NPB][DIM];
  const int tid  = threadIdx.x;
  const int lane = tid & 63;
  const int wv   = tid >> 6;
  const int g    = lane >> 4;
  const int q    = lane & 15;
  const int q8   = q << 3;
  const int n0   = blockIdx.x * NPB;
  const int e0   = offs[n0];
  const int nEnd = n0 + NPB < n ? n0 + NPB : n;
  const int nE   = offs[nEnd] - e0;
  for (int i = tid; i < nE && i < LDSE; i += 256) eds[i] = edata[e0 + i];
  for (int i = tid; i < DIM * NCLS; i += 256) {
    int k = i / NCLS, cls = i - k * NCLS;
    t2s[i] = t2w[cls * DIM + k];
  }
  __syncthreads();

  const int node = n0 + wv * 4 + g;
  int s = 0, cnt = 0;
  if (node < n) { s = offs[node] - e0; cnt = offs[node + 1] - e0 - s; }
  int mcnt = cnt;
  mcnt = max(mcnt, __shfl_xor(mcnt, 16, 64));
  mcnt = max(mcnt, __shfl_xor(mcnt, 32, 64));

  float4 acc = {0.f, 0.f, 0.f, 0.f};
  if (nE <= LDSE) { EDGE_LOOP(RD_LDS) } else { EDGE_LOOP(RD_GLB) }

  if (node >= n) return;
  const int nl = wv * 4 + g;
  {
    uint2 rv = *reinterpret_cast<const uint2*>((const char*)rawb + (size_t)node * 128 + q8);
    float4 v;
    v.x = fmaf(EPS_FA, __uint_as_float(rv.x << 16),         acc.x);
    v.y = fmaf(EPS_FA, __uint_as_float(rv.x & 0xffff0000u), acc.y);
    v.z = fmaf(EPS_FA, __uint_as_float(rv.y << 16),         acc.z);
    v.w = fmaf(EPS_FA, __uint_as_float(rv.y & 0xffff0000u), acc.w);
    *reinterpret_cast<float4*>(&rowbuf[nl][q * 4]) = v;   // wave-local: in-order DS pipe
  }
  // classifier: lane q handles classes q, q+16, q+32 for its group's node
  int c0 = q, c1 = q + 16, c2 = q + 32;
  int c2c = c2 < NCLS ? c2 : 0;                 // clamp (lane masked at output)
  float lg0 = t2b[c0], lg1 = t2b[c1], lg2 = t2b[c2c];
#pragma unroll
  for (int k = 0; k < DIM; ++k) {
    float r = rowbuf[nl][k];
    lg0 = fmaf(r, t2s[k * NCLS + c0], lg0);
    lg1 = fmaf(r, t2s[k * NCLS + c1], lg1);
    lg2 = fmaf(r, t2s[k * NCLS + c2c], lg2);
  }
  bool v2ok = c2 < NCLS;
  float mx = fmaxf(fmaxf(lg0, lg1), v2ok ? lg2 : -1e30f);
#pragma unroll
  for (int off = 8; off > 0; off >>= 1) mx = fmaxf(mx, __shfl_xor(mx, off, 64));
  float ssum = __expf(lg0 - mx) + __expf(lg1 - mx) + (v2ok ? __expf(lg2 - mx) : 0.f);
#pragma unroll
  for (int off = 8; off > 0; off >>= 1) ssum += __shfl_xor(ssum, off, 64);
  float lse = mx + __logf(ssum);
  float* op = out + (size_t)node * NCLS;
  op[c0] = lg0 - lse;
  op[c1] = lg1 - lse;
  if (v2ok) op[c2] = lg2 - lse;
}

// ---------------- launch ----------------

extern "C" void kernel_launch(void* const* d_in, const int* in_sizes, int n_in,
                              void* d_out, int out_size, void* d_ws, size_t ws_size,
                              hipStream_t stream) {
  const float* x   = (const float*)d_in[0];
  const int*   ei  = (const int*)d_in[1];
  const float* ewt = (const float*)d_in[2];
  const float* t1w = (const float*)d_in[3];
  const float* t1b = (const float*)d_in[4];
  const float* al1 = (const float*)d_in[5];
  const float* ar1 = (const float*)d_in[6];
  const float* al2 = (const float*)d_in[7];
  const float* ar2 = (const float*)d_in[8];
  const float* t2w = (const float*)d_in[9];
  const float* t2b = (const float*)d_in[10];
  float* out = (float*)d_out;

  const int n = in_sizes[0] / NFEAT;   // 100000
  const int E = in_sizes[2];           // 1600000
  const int* srcp = ei;
  const int* dstp = ei + E;

  char* p = (char*)d_ws;
  auto alloc = [&](size_t bytes) {
    char* q = p;
    p += (bytes + 255) & ~(size_t)255;
    return q;
  };
  unsigned short* h0b = (unsigned short*)alloc((size_t)n * DIM * 2);
  unsigned short* h1b = (unsigned short*)alloc((size_t)n * DIM * 2);
  float* hl    = (float*)alloc((size_t)n * 4);
  float* hr    = (float*)alloc((size_t)n * 4);
  int*   offs  = (int*)alloc((size_t)(n + 1) * 4);
  int*   srcs  = (int*)alloc((size_t)E * 4);
  int*   dsts  = (int*)alloc((size_t)E * 4);
  float* ew2   = (float*)alloc((size_t)E * 4);
  int2*  edata = (int2*)alloc((size_t)E * 8);
  // transients live inside the (not-yet-live) edata region
  int* deg    = (int*)edata;                       // n*4 = 400 KB
  int* cursor = (int*)((char*)edata + 0x80000);    // +512 KB
  int* bsums  = (int*)((char*)edata + 0x100000);   // +1 MB, 4 KB

  const int nb = (n + 1023) / 1024;
  const int eb = (E + 255) / 256;

  hipMemsetAsync(deg, 0, (size_t)n * 4, stream);
  hipMemsetAsync(cursor, 0, (size_t)n * 4, stream);

  hist_kernel<<<eb, 256, 0, stream>>>(dstp, deg, E);
  scan_block_kernel<<<nb, 1024, 0, stream>>>(deg, offs, bsums, n);
  scan_sums_kernel<<<1, 64, 0, stream>>>(bsums, nb, offs, n);
  scan_add_kernel<<<nb, 1024, 0, stream>>>(offs, bsums, n);
  scatter_kernel<<<eb, 256, 0, stream>>>(srcp, dstp, ewt, offs, cursor,
                                         srcs, dsts, ew2, E);

  gemm1_kernel<<<(n + 63) / 64, 256, 0, stream>>>(x, t1w, t1b, h0b, n);
  dots_kernel<<<(n + 3) / 4, 256, 0, stream>>>(h0b, al1, ar1, hl, hr, n);
  coef_kernel<<<eb, 256, 0, stream>>>(srcs, dsts, ew2, hl, hr, edata, E);

  const int ab = (n + NPB - 1) / NPB;
  agg1_kernel<<<ab, 256, 0, stream>>>(h0b, edata, offs, al2, ar2, h1b, hl, hr, n);
  coef_kernel<<<eb, 256, 0, stream>>>(srcs, dsts, ew2, hl, hr, edata, E);
  agg_cls_kernel<<<ab, 256, 0, stream>>>(h1b, h0b, edata, offs, t2w, t2b, out, n);
}

// Round 5
// 347.232 us; speedup vs baseline: 2.9622x; 1.2637x over previous
//
#include <hip/hip_runtime.h>
#include <hip/hip_bf16.h>

#define NFEAT 500
#define DIM   64
#define NCLS  40
#define EPS_FA 0.3f
#define NPB   16      // nodes per agg block (4 waves x 4 groups)
#define LDSE  1024    // staged edges per block (mean 256; Poisson(256) never nears 1024)

typedef __attribute__((ext_vector_type(8))) __bf16 bf16x8;
typedef __attribute__((ext_vector_type(4))) float  f32x4;

__device__ __forceinline__ float bf2f(unsigned short u) {
  return __uint_as_float(((unsigned int)u) << 16);
}
__device__ __forceinline__ float fast_tanh(float x) {
  return 1.f - 2.f / (__expf(2.f * x) + 1.f);
}
__device__ __forceinline__ unsigned int packbf(float a, float b) {
  __bf16 x = (__bf16)a, y = (__bf16)b;
  unsigned short ux = *(unsigned short*)&x, uy = *(unsigned short*)&y;
  return (unsigned int)ux | ((unsigned int)uy << 16);
}

// ---------------- CSR build ----------------

__global__ __launch_bounds__(256) void hist_kernel(const int* __restrict__ dst,
                                                   int* __restrict__ deg, int E) {
  int e = blockIdx.x * 256 + threadIdx.x;
  if (e < E) atomicAdd(&deg[dst[e]], 1);
}

__global__ __launch_bounds__(1024) void scan_block_kernel(const int* __restrict__ deg,
                                                          int* __restrict__ offs,
                                                          int* __restrict__ bsums, int n) {
  __shared__ int s[1024];
  int t = threadIdx.x;
  int i = blockIdx.x * 1024 + t;
  int v = (i < n) ? deg[i] : 0;
  s[t] = v;
  __syncthreads();
  for (int off = 1; off < 1024; off <<= 1) {
    int add = (t >= off) ? s[t - off] : 0;
    __syncthreads();
    s[t] += add;
    __syncthreads();
  }
  if (i < n) offs[i] = s[t] - v;
  if (t == 1023) bsums[blockIdx.x] = s[1023];
}

__global__ void scan_sums_kernel(int* __restrict__ bsums, int nb,
                                 int* __restrict__ offs, int n) {
  if (blockIdx.x == 0 && threadIdx.x == 0) {
    int run = 0;
    for (int i = 0; i < nb; ++i) { int v = bsums[i]; bsums[i] = run; run += v; }
    offs[n] = run;
  }
}

__global__ __launch_bounds__(1024) void scan_add_kernel(int* __restrict__ offs,
                                                        const int* __restrict__ bsums, int n) {
  int i = blockIdx.x * 1024 + threadIdx.x;
  if (i < n) offs[i] += bsums[blockIdx.x];
}

// scatter ONE 8B record per edge into CSR order: {src, masked sigmoid(w)}
__global__ __launch_bounds__(256) void scatter_kernel(const int* __restrict__ src,
                                                      const int* __restrict__ dst,
                                                      const float* __restrict__ ewt,
                                                      const int* __restrict__ offs,
                                                      int* __restrict__ cursor,
                                                      int2* __restrict__ edata, int E) {
  int e = blockIdx.x * 256 + threadIdx.x;
  if (e >= E) return;
  int d = dst[e];
  int pos = offs[d] + atomicAdd(&cursor[d], 1);
  float w = ewt[e];
  float sg = (__builtin_fabsf(w) > 0.f) ? (1.f / (1.f + __expf(-w))) : 0.f;
  edata[pos] = make_int2(src[e], __float_as_int(sg));
}

// ---------------- GEMM1: h = relu(x @ w^T + b), split-bf16 MFMA, fused L1 dots ----------------

__global__ __launch_bounds__(256) void gemm1_kernel(const float* __restrict__ x,
                                                    const float* __restrict__ w,
                                                    const float* __restrict__ bias,
                                                    const float* __restrict__ al,
                                                    const float* __restrict__ ar,
                                                    unsigned short* __restrict__ hb,
                                                    float* __restrict__ hl,
                                                    float* __restrict__ hr, int n) {
  __shared__ __bf16 Ah[64][72], Al[64][72], Bh[64][72], Bl[64][72];
  const int tid  = threadIdx.x;
  const int lane = tid & 63;
  const int wv   = tid >> 6;
  const int m0   = blockIdx.x * 64;

  f32x4 acc[4];
#pragma unroll
  for (int c = 0; c < 4; ++c) acc[c] = (f32x4){0.f, 0.f, 0.f, 0.f};

  const int rowA = wv * 16 + (lane & 15);
  const int koff = (lane >> 4) * 8;

  for (int kb = 0; kb < 512; kb += 64) {
#pragma unroll
    for (int r = 0; r < 4; ++r) {
      int idx = r * 256 + tid;
      int m   = idx >> 4;
      int k4  = (idx & 15) << 2;
      int gk  = kb + k4;
      float4 va = {0.f, 0.f, 0.f, 0.f};
      int gm = m0 + m;
      if (gm < n && gk < NFEAT)
        va = *reinterpret_cast<const float4*>(&x[(size_t)gm * NFEAT + gk]);
      float4 vb = {0.f, 0.f, 0.f, 0.f};
      if (gk < NFEAT)
        vb = *reinterpret_cast<const float4*>(&w[(size_t)m * NFEAT + gk]);
#pragma unroll
      for (int q = 0; q < 4; ++q) {
        float fa = (&va.x)[q];
        __bf16 ah = (__bf16)fa;
        Ah[m][k4 + q] = ah;
        Al[m][k4 + q] = (__bf16)(fa - (float)ah);
        float fb = (&vb.x)[q];
        __bf16 bh = (__bf16)fb;
        Bh[m][k4 + q] = bh;
        Bl[m][k4 + q] = (__bf16)(fb - (float)bh);
      }
    }
    __syncthreads();
#pragma unroll
    for (int ks = 0; ks < 2; ++ks) {
      int k0 = ks * 32 + koff;
      bf16x8 a_h = *reinterpret_cast<const bf16x8*>(&Ah[rowA][k0]);
      bf16x8 a_l = *reinterpret_cast<const bf16x8*>(&Al[rowA][k0]);
#pragma unroll
      for (int c = 0; c < 4; ++c) {
        int rb = c * 16 + (lane & 15);
        bf16x8 b_h = *reinterpret_cast<const bf16x8*>(&Bh[rb][k0]);
        bf16x8 b_l = *reinterpret_cast<const bf16x8*>(&Bl[rb][k0]);
        acc[c] = __builtin_amdgcn_mfma_f32_16x16x32_bf16(a_h, b_h, acc[c], 0, 0, 0);
        acc[c] = __builtin_amdgcn_mfma_f32_16x16x32_bf16(a_h, b_l, acc[c], 0, 0, 0);
        acc[c] = __builtin_amdgcn_mfma_f32_16x16x32_bf16(a_l, b_h, acc[c], 0, 0, 0);
      }
    }
    __syncthreads();
  }

  float rowa[4] = {0.f, 0.f, 0.f, 0.f};
  float rowb[4] = {0.f, 0.f, 0.f, 0.f};
#pragma unroll
  for (int c = 0; c < 4; ++c) {
    int col = c * 16 + (lane & 15);
    float bv = bias[col], alc = al[col], arc = ar[col];
#pragma unroll
    for (int r = 0; r < 4; ++r) {
      int gm = m0 + wv * 16 + (lane >> 4) * 4 + r;
      float v = acc[c][r] + bv;
      v = v > 0.f ? v : 0.f;
      if (gm < n) {
        __bf16 vb16 = (__bf16)v;
        hb[(size_t)gm * DIM + col] = *reinterpret_cast<unsigned short*>(&vb16);
      }
      rowa[r] = fmaf(v, alc, rowa[r]);
      rowb[r] = fmaf(v, arc, rowb[r]);
    }
  }
  // L1 attention dots: reduce over the 16-lane subgroup owning each row
#pragma unroll
  for (int r = 0; r < 4; ++r) {
    float a = rowa[r], b = rowb[r];
#pragma unroll
    for (int off = 8; off > 0; off >>= 1) {
      a += __shfl_xor(a, off, 64);
      b += __shfl_xor(b, off, 64);
    }
    if ((lane & 15) == 0) {
      int gm = m0 + wv * 16 + (lane >> 4) * 4 + r;
      if (gm < n) { hl[gm] = a; hr[gm] = b; }
    }
  }
}

// ---------------- 4-stream edge loop (one 16-lane group per node) ----------------
// Staged LDS format: {src_byte_off, coef}. Global fallback computes coef inline.

#define EDGE_LOOP(READ_ED)                                                   \
  for (int j = 0; j < mcnt; j += 8) {                                        \
    _Pragma("unroll")                                                        \
    for (int u = 0; u < 8; ++u) {                                            \
      int idx = j + u;                                                       \
      bool valid = idx < cnt;                                                \
      int ci = valid ? s + idx : 0;                                          \
      int2 ed = READ_ED(ci);                                                 \
      int off = valid ? ed.x : 0;                                            \
      float cf = valid ? __int_as_float(ed.y) : 0.f;                         \
      uint2 hv = *reinterpret_cast<const uint2*>((const char*)hb + off + q8);\
      acc.x = fmaf(cf, __uint_as_float(hv.x << 16), acc.x);                  \
      acc.y = fmaf(cf, __uint_as_float(hv.x & 0xffff0000u), acc.y);          \
      acc.z = fmaf(cf, __uint_as_float(hv.y << 16), acc.z);                  \
      acc.w = fmaf(cf, __uint_as_float(hv.y & 0xffff0000u), acc.w);          \
    }                                                                        \
  }
#define RD_LDS(ci) eds[ci]
#define RD_GLB(ci) ({ int2 _e = edata[e0 + (ci)];                            \
      float _c = fast_tanh(hlv[_e.x] + hrd) * __int_as_float(_e.y);          \
      make_int2(_e.x * 128, __float_as_int(_c)); })

// block-cooperative staging with inline coef (dst found by 4-step binary search)
#define STAGE_EDGES(HLV, HRL)                                                \
  for (int i = tid; i < nE && i < LDSE; i += 256) {                          \
    int2 e = edata[e0 + i];                                                  \
    int key = e0 + i;                                                        \
    int nd = 0;                                                              \
    _Pragma("unroll")                                                        \
    for (int st = 8; st >= 1; st >>= 1)                                      \
      if (offs_l[nd + st] <= key) nd += st;                                  \
    float c = fast_tanh(HLV[e.x] + HRL[nd]) * __int_as_float(e.y);           \
    eds[i] = make_int2(e.x * 128, __float_as_int(c));                        \
  }

// ---------------- FAConv layer-1 agg + fused layer-2 dots ----------------

__global__ __launch_bounds__(256) void agg1_kernel(const unsigned short* __restrict__ hb,
                                                   const int2* __restrict__ edata,
                                                   const int* __restrict__ offs,
                                                   const float* __restrict__ hlv,
                                                   const float* __restrict__ hrv,
                                                   const float* __restrict__ al2,
                                                   const float* __restrict__ ar2,
                                                   unsigned short* __restrict__ h1b,
                                                   float* __restrict__ hl2,
                                                   float* __restrict__ hr2, int n) {
  __shared__ int2 eds[LDSE];
  __shared__ int offs_l[NPB + 1];
  __shared__ float hr_l[NPB];
  const int tid  = threadIdx.x;
  const int lane = tid & 63;
  const int wv   = tid >> 6;
  const int g    = lane >> 4;
  const int q    = lane & 15;
  const int q8   = q << 3;
  const int n0   = blockIdx.x * NPB;
  if (tid <= NPB) {
    int nd = n0 + tid;
    offs_l[tid] = offs[nd < n ? nd : n];
  }
  if (tid < NPB) {
    int nd = n0 + tid;
    hr_l[tid] = nd < n ? hrv[nd] : 0.f;
  }
  __syncthreads();
  const int e0 = offs_l[0];
  const int nE = offs_l[NPB] - e0;
  STAGE_EDGES(hlv, hr_l)
  __syncthreads();

  const int node = n0 + wv * 4 + g;
  int s = 0, cnt = 0;
  float hrd = 0.f;
  if (node < n) {
    s = offs_l[wv * 4 + g] - e0;
    cnt = offs_l[wv * 4 + g + 1] - e0 - s;
    hrd = hr_l[wv * 4 + g];
  }
  int mcnt = cnt;
  mcnt = max(mcnt, __shfl_xor(mcnt, 16, 64));
  mcnt = max(mcnt, __shfl_xor(mcnt, 32, 64));

  float4 acc = {0.f, 0.f, 0.f, 0.f};
  if (nE <= LDSE) { EDGE_LOOP(RD_LDS) } else { EDGE_LOOP(RD_GLB) }

  if (node < n) {
    uint2 rv = *reinterpret_cast<const uint2*>((const char*)hb + (size_t)node * 128 + q8);
    float v0 = fmaf(EPS_FA, __uint_as_float(rv.x << 16),         acc.x);
    float v1 = fmaf(EPS_FA, __uint_as_float(rv.x & 0xffff0000u), acc.y);
    float v2 = fmaf(EPS_FA, __uint_as_float(rv.y << 16),         acc.z);
    float v3 = fmaf(EPS_FA, __uint_as_float(rv.y & 0xffff0000u), acc.w);
    uint2 pk = make_uint2(packbf(v0, v1), packbf(v2, v3));
    *reinterpret_cast<uint2*>((char*)h1b + (size_t)node * 128 + q8) = pk;
    const float4 alv = *reinterpret_cast<const float4*>(al2 + q * 4);
    const float4 arv = *reinterpret_cast<const float4*>(ar2 + q * 4);
    float a = v0 * alv.x + v1 * alv.y + v2 * alv.z + v3 * alv.w;
    float b = v0 * arv.x + v1 * arv.y + v2 * arv.z + v3 * arv.w;
#pragma unroll
    for (int off = 8; off > 0; off >>= 1) {
      a += __shfl_xor(a, off, 64);
      b += __shfl_xor(b, off, 64);
    }
    if (q == 0) { hl2[node] = a; hr2[node] = b; }
  }
}

// ---------------- layer-2 agg fused with classifier + log_softmax ----------------

__global__ __launch_bounds__(256) void agg_cls_kernel(const unsigned short* __restrict__ hb,
                                                      const unsigned short* __restrict__ rawb,
                                                      const int2* __restrict__ edata,
                                                      const int* __restrict__ offs,
                                                      const float* __restrict__ hlv,
                                                      const float* __restrict__ hrv,
                                                      const float* __restrict__ t2w,
                                                      const float* __restrict__ t2b,
                                                      float* __restrict__ out, int n) {
  __shared__ int2 eds[LDSE];
  __shared__ int offs_l[NPB + 1];
  __shared__ float hr_l[NPB];
  __shared__ float t2s[DIM * NCLS];     // [k][cls]
  __shared__ float rowbuf[NPB][DIM];
  const int tid  = threadIdx.x;
  const int lane = tid & 63;
  const int wv   = tid >> 6;
  const int g    = lane >> 4;
  const int q    = lane & 15;
  const int q8   = q << 3;
  const int n0   = blockIdx.x * NPB;
  if (tid <= NPB) {
    int nd = n0 + tid;
    offs_l[tid] = offs[nd < n ? nd : n];
  }
  if (tid < NPB) {
    int nd = n0 + tid;
    hr_l[tid] = nd < n ? hrv[nd] : 0.f;
  }
  for (int i = tid; i < DIM * NCLS; i += 256) {
    int k = i / NCLS, cls = i - k * NCLS;
    t2s[i] = t2w[cls * DIM + k];
  }
  __syncthreads();
  const int e0 = offs_l[0];
  const int nE = offs_l[NPB] - e0;
  STAGE_EDGES(hlv, hr_l)
  __syncthreads();

  const int node = n0 + wv * 4 + g;
  int s = 0, cnt = 0;
  float hrd = 0.f;
  if (node < n) {
    s = offs_l[wv * 4 + g] - e0;
    cnt = offs_l[wv * 4 + g + 1] - e0 - s;
    hrd = hr_l[wv * 4 + g];
  }
  int mcnt = cnt;
  mcnt = max(mcnt, __shfl_xor(mcnt, 16, 64));
  mcnt = max(mcnt, __shfl_xor(mcnt, 32, 64));

  float4 acc = {0.f, 0.f, 0.f, 0.f};
  if (nE <= LDSE) { EDGE_LOOP(RD_LDS) } else { EDGE_LOOP(RD_GLB) }

  if (node >= n) return;
  const int nl = wv * 4 + g;
  {
    uint2 rv = *reinterpret_cast<const uint2*>((const char*)rawb + (size_t)node * 128 + q8);
    float4 v;
    v.x = fmaf(EPS_FA, __uint_as_float(rv.x << 16),         acc.x);
    v.y = fmaf(EPS_FA, __uint_as_float(rv.x & 0xffff0000u), acc.y);
    v.z = fmaf(EPS_FA, __uint_as_float(rv.y << 16),         acc.z);
    v.w = fmaf(EPS_FA, __uint_as_float(rv.y & 0xffff0000u), acc.w);
    *reinterpret_cast<float4*>(&rowbuf[nl][q * 4]) = v;   // wave-local: in-order DS pipe
  }
  int c0 = q, c1 = q + 16, c2 = q + 32;
  int c2c = c2 < NCLS ? c2 : 0;
  float lg0 = t2b[c0], lg1 = t2b[c1], lg2 = t2b[c2c];
#pragma unroll
  for (int k = 0; k < DIM; ++k) {
    float r = rowbuf[nl][k];
    lg0 = fmaf(r, t2s[k * NCLS + c0], lg0);
    lg1 = fmaf(r, t2s[k * NCLS + c1], lg1);
    lg2 = fmaf(r, t2s[k * NCLS + c2c], lg2);
  }
  bool v2ok = c2 < NCLS;
  float mx = fmaxf(fmaxf(lg0, lg1), v2ok ? lg2 : -1e30f);
#pragma unroll
  for (int off = 8; off > 0; off >>= 1) mx = fmaxf(mx, __shfl_xor(mx, off, 64));
  float ssum = __expf(lg0 - mx) + __expf(lg1 - mx) + (v2ok ? __expf(lg2 - mx) : 0.f);
#pragma unroll
  for (int off = 8; off > 0; off >>= 1) ssum += __shfl_xor(ssum, off, 64);
  float lse = mx + __logf(ssum);
  float* op = out + (size_t)node * NCLS;
  op[c0] = lg0 - lse;
  op[c1] = lg1 - lse;
  if (v2ok) op[c2] = lg2 - lse;
}

// ---------------- launch ----------------

extern "C" void kernel_launch(void* const* d_in, const int* in_sizes, int n_in,
                              void* d_out, int out_size, void* d_ws, size_t ws_size,
                              hipStream_t stream) {
  const float* x   = (const float*)d_in[0];
  const int*   ei  = (const int*)d_in[1];
  const float* ewt = (const float*)d_in[2];
  const float* t1w = (const float*)d_in[3];
  const float* t1b = (const float*)d_in[4];
  const float* al1 = (const float*)d_in[5];
  const float* ar1 = (const float*)d_in[6];
  const float* al2 = (const float*)d_in[7];
  const float* ar2 = (const float*)d_in[8];
  const float* t2w = (const float*)d_in[9];
  const float* t2b = (const float*)d_in[10];
  float* out = (float*)d_out;

  const int n = in_sizes[0] / NFEAT;   // 100000
  const int E = in_sizes[2];           // 1600000
  const int* srcp = ei;
  const int* dstp = ei + E;

  char* p = (char*)d_ws;
  auto alloc = [&](size_t bytes) {
    char* q = p;
    p += (bytes + 255) & ~(size_t)255;
    return q;
  };
  unsigned short* h0b = (unsigned short*)alloc((size_t)n * DIM * 2);
  unsigned short* h1b = (unsigned short*)alloc((size_t)n * DIM * 2);
  float* hl    = (float*)alloc((size_t)n * 4);
  float* hr    = (float*)alloc((size_t)n * 4);
  float* hl2   = (float*)alloc((size_t)n * 4);
  float* hr2   = (float*)alloc((size_t)n * 4);
  int*   offs  = (int*)alloc((size_t)(n + 1) * 4);
  int2*  edata = (int2*)alloc((size_t)E * 8);
  int*   deg   = (int*)alloc((size_t)n * 4);
  int*   cursor= (int*)alloc((size_t)n * 4);
  int*   bsums = (int*)alloc(4096);

  const int nb = (n + 1023) / 1024;
  const int eb = (E + 255) / 256;

  hipMemsetAsync(deg, 0, (size_t)n * 4, stream);
  hipMemsetAsync(cursor, 0, (size_t)n * 4, stream);

  hist_kernel<<<eb, 256, 0, stream>>>(dstp, deg, E);
  scan_block_kernel<<<nb, 1024, 0, stream>>>(deg, offs, bsums, n);
  scan_sums_kernel<<<1, 64, 0, stream>>>(bsums, nb, offs, n);
  scan_add_kernel<<<nb, 1024, 0, stream>>>(offs, bsums, n);
  scatter_kernel<<<eb, 256, 0, stream>>>(srcp, dstp, ewt, offs, cursor, edata, E);

  gemm1_kernel<<<(n + 63) / 64, 256, 0, stream>>>(x, t1w, t1b, al1, ar1, h0b, hl, hr, n);

  const int ab = (n + NPB - 1) / NPB;
  agg1_kernel<<<ab, 256, 0, stream>>>(h0b, edata, offs, hl, hr, al2, ar2, h1b, hl2, hr2, n);
  agg_cls_kernel<<<ab, 256, 0, stream>>>(h1b, h0b, edata, offs, hl2, hr2, t2w, t2b, out, n);
}